// Round 10
// baseline (4912.365 us; speedup 1.0000x reference)
//
#include <hip/hip_runtime.h>
#include <hip/hip_fp16.h>
#include <stdint.h>

#define TT 2048
#define BB 16
#define DD 1024
static const size_t H0OFF = 33554432; // 2048*16*1024 floats (start of h section in d_out)

// partial-exchange layout
#define PSTRIDE 1040                  // words per peer array (1024 + 16 pad -> L2 channel spread)
#define PB (16 * PSTRIDE)             // words per batch (16 peers)
#define SLOTW (16 * PB)               // words per ring slot (16 batches)

typedef _Float16 f16;
typedef _Float16 f16x2 __attribute__((ext_vector_type(2)));
typedef _Float16 f16x8 __attribute__((ext_vector_type(8)));
typedef float f32x4 __attribute__((ext_vector_type(4)));
typedef unsigned u32x4 __attribute__((ext_vector_type(4)));

// ---------------- threefry + normal (replicates jax.random.normal(key(1),(1024,),f32)) ----
__device__ __forceinline__ float erfinv_xla(float x) {
  float w = -log1pf(-x * x);
  float p;
  if (w < 5.0f) {
    w -= 2.5f;
    p = 2.81022636e-08f;
    p = fmaf(p, w, 3.43273939e-07f);
    p = fmaf(p, w, -3.5233877e-06f);
    p = fmaf(p, w, -4.39150654e-06f);
    p = fmaf(p, w, 0.00021858087f);
    p = fmaf(p, w, -0.00125372503f);
    p = fmaf(p, w, -0.00417768164f);
    p = fmaf(p, w, 0.246640727f);
    p = fmaf(p, w, 1.50140941f);
  } else {
    w = sqrtf(w) - 3.0f;
    p = -0.000200214257f;
    p = fmaf(p, w, 0.000100950558f);
    p = fmaf(p, w, 0.00134934322f);
    p = fmaf(p, w, -0.00367342844f);
    p = fmaf(p, w, 0.00573950773f);
    p = fmaf(p, w, -0.0076224613f);
    p = fmaf(p, w, 0.00943887047f);
    p = fmaf(p, w, 1.00167406f);
    p = fmaf(p, w, 2.83297682f);
  }
  return p * x;
}

__device__ __forceinline__ float bits_to_normal(unsigned bits) {
  unsigned fb = (bits >> 9) | 0x3f800000u;
  float f = __uint_as_float(fb) - 1.0f;          // [0,1)
  const float lo = -0.99999994f;                 // nextafterf(-1,0)
  float u = f * 2.0f + lo;
  u = fmaxf(lo, u);
  return __uint_as_float(0x3fb504f3u) * erfinv_xla(u); // sqrt(2) fp32
}

#define TF_ROUND(r) { x0 += x1; x1 = (x1 << r) | (x1 >> (32 - r)); x1 ^= x0; }

__global__ void k_u0(float* t0, float* u) {
  __shared__ float red[512];
  int i = threadIdx.x; // 512 threads
  unsigned ks0 = 0u, ks1 = 1u, ks2 = 0x1BD11BDAu ^ 0u ^ 1u;
  unsigned x0 = (unsigned)i + ks0;
  unsigned x1 = (unsigned)(i + 512) + ks1;
  TF_ROUND(13) TF_ROUND(15) TF_ROUND(26) TF_ROUND(6)
  x0 += ks1; x1 += ks2 + 1u;
  TF_ROUND(17) TF_ROUND(29) TF_ROUND(16) TF_ROUND(24)
  x0 += ks2; x1 += ks0 + 2u;
  TF_ROUND(13) TF_ROUND(15) TF_ROUND(26) TF_ROUND(6)
  x0 += ks0; x1 += ks1 + 3u;
  TF_ROUND(17) TF_ROUND(29) TF_ROUND(16) TF_ROUND(24)
  x0 += ks1; x1 += ks2 + 4u;
  TF_ROUND(13) TF_ROUND(15) TF_ROUND(26) TF_ROUND(6)
  x0 += ks2; x1 += ks0 + 5u;
  float z0 = bits_to_normal(x0);
  float z1 = bits_to_normal(x1);
  t0[i] = z0; t0[i + 512] = z1;
  red[i] = z0 * z0 + z1 * z1;
  __syncthreads();
  for (int s = 256; s > 0; s >>= 1) { if (i < s) red[i] += red[i + s]; __syncthreads(); }
  float inv = 1.0f / sqrtf(red[0]);
  u[i] = t0[i] * inv; u[i + 512] = t0[i + 512] * inv;
}

// ---------------- power iteration helpers ----------------
__global__ void k_mvT(const float* __restrict__ W, const float* __restrict__ u,
                      float* __restrict__ out) { // out[j] = sum_i W[i,j]*u[i]
  int j = blockIdx.x * 256 + threadIdx.x;
  float acc = 0.f;
  for (int i = 0; i < DD; ++i) acc = fmaf(W[(size_t)i * DD + j], u[i], acc);
  out[j] = acc;
}

__global__ void k_mv(const float* __restrict__ W, const float* __restrict__ v,
                     float* __restrict__ out) { // out[i] = sum_j W[i,j]*v[j]
  int gtid = blockIdx.x * 256 + threadIdx.x;
  int wave = gtid >> 6, lane = threadIdx.x & 63;
  for (int rr = 0; rr < 16; ++rr) {
    int row = wave * 16 + rr;
    float acc = 0.f;
    for (int c = 0; c < 16; ++c) {
      int col = c * 64 + lane;
      acc = fmaf(W[(size_t)row * DD + col], v[col], acc);
    }
    for (int off = 32; off > 0; off >>= 1) acc += __shfl_down(acc, off, 64);
    if (lane == 0) out[row] = acc;
  }
}

__global__ void k_norm(const float* __restrict__ src, float* __restrict__ dst, float eps) {
  __shared__ float red[1024];
  int i = threadIdx.x;
  float xv = src[i];
  red[i] = xv * xv;
  __syncthreads();
  for (int s = 512; s > 0; s >>= 1) { if (i < s) red[i] += red[i + s]; __syncthreads(); }
  float inv = 1.0f / (sqrtf(red[0]) + eps);
  dst[i] = src[i] * inv;
}

__global__ void k_sigma(const float* __restrict__ u, const float* __restrict__ wv,
                        float* __restrict__ scale) {
  __shared__ float red[1024];
  int i = threadIdx.x;
  red[i] = u[i] * wv[i];
  __syncthreads();
  for (int s = 512; s > 0; s >>= 1) { if (i < s) red[i] += red[i + s]; __syncthreads(); }
  if (i == 0) scale[0] = 0.99f / (fabsf(red[0]) + 1e-8f);
}

__global__ void k_castWh(const float* __restrict__ Wh, const float* __restrict__ scale,
                         f16* __restrict__ WhH) {
  int i = blockIdx.x * 256 + threadIdx.x;
  float s = scale[0];
  WhH[i] = (f16)(Wh[i] * s);
}

// ---------------- batched GEMM: C[m,e] = sum_d X[m,d]*W[e,d] + bias[e] (W in f32) ------
__global__ __launch_bounds__(256) void k_gemm(const float* __restrict__ X,
                                              const float* __restrict__ Wt,
                                              const float* __restrict__ bias,
                                              float* __restrict__ Cout) {
  __shared__ __align__(16) f16 Ah[128 * 64];
  __shared__ __align__(16) f16 Bh[128 * 64];
  int m0 = blockIdx.x * 128, n0 = blockIdx.y * 128;
  int tid = threadIdx.x, lane = tid & 63, w = tid >> 6;
  int wm = w & 1, wn = w >> 1;
  int srow = tid >> 3, scol = (tid & 7) * 8;
  f32x4 acc[4][4];
#pragma unroll
  for (int i = 0; i < 4; ++i)
#pragma unroll
    for (int j = 0; j < 4; ++j) acc[i][j] = (f32x4){0.f, 0.f, 0.f, 0.f};

  for (int kt = 0; kt < 16; ++kt) {
    int k0 = kt * 64;
#pragma unroll
    for (int c = 0; c < 4; ++c) {
      int row = c * 32 + srow;
      const float4* sa = (const float4*)(X + (size_t)(m0 + row) * DD + k0 + scol);
      float4 a0 = sa[0], a1 = sa[1];
      f16x8 hv;
      hv[0] = (f16)a0.x; hv[1] = (f16)a0.y; hv[2] = (f16)a0.z; hv[3] = (f16)a0.w;
      hv[4] = (f16)a1.x; hv[5] = (f16)a1.y; hv[6] = (f16)a1.z; hv[7] = (f16)a1.w;
      *(f16x8*)&Ah[row * 64 + scol] = hv;
      const float4* sb = (const float4*)(Wt + (size_t)(n0 + row) * DD + k0 + scol);
      float4 b0 = sb[0], b1 = sb[1];
      f16x8 hw;
      hw[0] = (f16)b0.x; hw[1] = (f16)b0.y; hw[2] = (f16)b0.z; hw[3] = (f16)b0.w;
      hw[4] = (f16)b1.x; hw[5] = (f16)b1.y; hw[6] = (f16)b1.z; hw[7] = (f16)b1.w;
      *(f16x8*)&Bh[row * 64 + scol] = hw;
    }
    __syncthreads();
#pragma unroll
    for (int ks = 0; ks < 2; ++ks) {
      f16x8 af[4], bf[4];
#pragma unroll
      for (int i = 0; i < 4; ++i)
        af[i] = *(const f16x8*)&Ah[(wm * 64 + i * 16 + (lane & 15)) * 64 + ks * 32 + (lane >> 4) * 8];
#pragma unroll
      for (int j = 0; j < 4; ++j)
        bf[j] = *(const f16x8*)&Bh[(wn * 64 + j * 16 + (lane & 15)) * 64 + ks * 32 + (lane >> 4) * 8];
#pragma unroll
      for (int i = 0; i < 4; ++i)
#pragma unroll
        for (int j = 0; j < 4; ++j)
          acc[i][j] = __builtin_amdgcn_mfma_f32_16x16x32_f16(af[i], bf[j], acc[i][j], 0, 0, 0);
    }
    __syncthreads();
  }
#pragma unroll
  for (int j = 0; j < 4; ++j) {
    int col = n0 + wn * 64 + j * 16 + (lane & 15);
    float bs = bias[col];
#pragma unroll
    for (int i = 0; i < 4; ++i) {
      int rbase = m0 + wm * 64 + i * 16 + (lane >> 4) * 4;
#pragma unroll
      for (int r = 0; r < 4; ++r)
        Cout[(size_t)(rbase + r) * DD + col] = acc[i][j][r] + bs;
    }
  }
}

// ---------------- persistent recurrence: partial-sum exchange ---------------------------
__device__ __forceinline__ float fdot2u(uint32_t a, uint32_t b, float c) {
#if __has_builtin(__builtin_amdgcn_fdot2)
  return __builtin_amdgcn_fdot2(__builtin_bit_cast(f16x2, a),
                                __builtin_bit_cast(f16x2, b), c, false);
#else
  f16x2 av = __builtin_bit_cast(f16x2, a), bv = __builtin_bit_cast(f16x2, b);
  return c + (float)av[0] * (float)bv[0] + (float)av[1] * (float)bv[1];
#endif
}

__device__ __forceinline__ float sigmoid_fast(float v) {
  return 1.0f / (1.0f + __expf(-v));
}
__device__ __forceinline__ float tanh_fast(float v) {
  float t = __expf(-2.0f * fabsf(v));
  float r = (1.0f - t) / (1.0f + t);
  return copysignf(r, v);
}

__device__ __forceinline__ uint32_t f16bits(float v) {
  return (uint32_t)__builtin_bit_cast(uint16_t, (f16)v);
}
__device__ __forceinline__ float f16val(uint32_t w) {
  return (float)__builtin_bit_cast(f16, (uint16_t)(w & 0xffffu));
}

// Block (batch, eslice) owns rows R = [64*es, 64*es+64) as BOTH gate outputs and matvec
// input dims. Per step: matvec uses only locally-produced h[R] (LDS, 256B); each wave
// publishes tagged f16 partials for its 128 output rows; wave0 polls 16 peers x 64 rows
// (16 pipelined loads/lane), sums, gates, stages h. One barrier per step.
__global__ __launch_bounds__(512, 1) void k_rec(const float* __restrict__ x,
                                                const float* __restrict__ h0,
                                                const float* __restrict__ b_gate,
                                                const f16* __restrict__ WhH,
                                                uint32_t* __restrict__ hx,
                                                float* __restrict__ d_out) {
  int bid = blockIdx.x;
  int batch = bid & 15;      // batch-mates share bid%8 -> one XCD under round-robin (perf only)
  int eslice = bid >> 4;     // 0..15
  int tid = threadIdx.x, lane = tid & 63, wv = tid >> 6;   // wv in [0,8)

  __shared__ uint32_t hls[2][32];    // h[R] as 32 f16-pairs, parity double-buffered

  // ---- W columns R for this wave's two output rows: e1 = 128*wv+lane, e2 = e1+64 ----
  int e1 = 128 * wv + lane, e2 = e1 + 64;
  u32x4 wA[8], wB[8];
  {
    const u32x4* p1 = (const u32x4*)(WhH + (size_t)e1 * DD + 64 * eslice);
    const u32x4* p2 = (const u32x4*)(WhH + (size_t)e2 * DD + 64 * eslice);
#pragma unroll
    for (int j = 0; j < 8; ++j) { wA[j] = p1[j]; wB[j] = p2[j]; }
  }
  asm volatile("" : "+v"(wA[0]), "+v"(wA[1]), "+v"(wA[2]), "+v"(wA[3]));
  asm volatile("" : "+v"(wA[4]), "+v"(wA[5]), "+v"(wA[6]), "+v"(wA[7]));
  asm volatile("" : "+v"(wB[0]), "+v"(wB[1]), "+v"(wB[2]), "+v"(wB[3]));
  asm volatile("" : "+v"(wB[4]), "+v"(wB[5]), "+v"(wB[6]), "+v"(wB[7]));

  // ---- wave0 prologue: h0 staging + tail state + t=0 streams ----
  float h_own = 0.f, bgv = 0.f, cx_c = 0.f, dr_c = 0.f, xv_c = 0.f;
  int e_g = 64 * eslice + lane;                // this block's global row for lane
  if (wv == 0) {
    __builtin_amdgcn_s_setprio(1);
    size_t b0 = (size_t)batch * DD + e_g;
    h_own = h0[b0];
    bgv = b_gate[e_g];
    d_out[H0OFF + b0] = h_own;                 // h[0]
    cx_c = d_out[b0];                          // cand_x[0]
    dr_c = d_out[H0OFF + 16384 + b0];          // delta_raw[0]
    xv_c = x[b0];
    float v0 = __shfl(h_own, 2 * (lane & 31), 64);
    float v1 = __shfl(h_own, 2 * (lane & 31) + 1, 64);
    if (lane < 32)
      hls[0][lane] = f16bits(v0) | (f16bits(v1) << 16);
  }
  __syncthreads();

  size_t pubrow = (size_t)batch * PB + (size_t)eslice * PSTRIDE;
  const uint32_t* pollbase = hx + (size_t)batch * PB + e_g;

#pragma unroll 1
  for (int t = 0; t < TT; ++t) {
    uint32_t tag = (uint32_t)(t + 1);
    // ---- all waves: matvec on local h(t), publish tagged partials ----
    {
      const u32x4* hl4 = (const u32x4*)&hls[t & 1][0];
      float a0 = 0.f, a1 = 0.f, b0 = 0.f, b1 = 0.f;
#pragma unroll
      for (int j = 0; j < 4; ++j) {
        u32x4 hh = hl4[j];
        a0 = fdot2u(wA[2 * j][0], hh[0], a0);     a0 = fdot2u(wA[2 * j][1], hh[1], a0);
        a0 = fdot2u(wA[2 * j][2], hh[2], a0);     a0 = fdot2u(wA[2 * j][3], hh[3], a0);
        b0 = fdot2u(wB[2 * j][0], hh[0], b0);     b0 = fdot2u(wB[2 * j][1], hh[1], b0);
        b0 = fdot2u(wB[2 * j][2], hh[2], b0);     b0 = fdot2u(wB[2 * j][3], hh[3], b0);
        u32x4 hg = hl4[j + 4];
        a1 = fdot2u(wA[2 * j + 1][0], hg[0], a1); a1 = fdot2u(wA[2 * j + 1][1], hg[1], a1);
        a1 = fdot2u(wA[2 * j + 1][2], hg[2], a1); a1 = fdot2u(wA[2 * j + 1][3], hg[3], a1);
        b1 = fdot2u(wB[2 * j + 1][0], hg[0], b1); b1 = fdot2u(wB[2 * j + 1][1], hg[1], b1);
        b1 = fdot2u(wB[2 * j + 1][2], hg[2], b1); b1 = fdot2u(wB[2 * j + 1][3], hg[3], b1);
      }
      // NOTE: hl4[j] pairs cols [8j..8j+8); wA[2j] covers cols [8j..8j+8)?  Mapping check:
      // wA[k] = cols [8k, 8k+8) as 4 f16-pairs; hl4[j] = pairs [4j, 4j+4) = cols [8j, 8j+8).
      // So wA[2j] must pair with hl4[2j].  Fixed below by using index k directly.
      // (loop above uses hl4[j] with wA[2j] -> WRONG; rewritten correctly:)
      a0 = 0.f; a1 = 0.f; b0 = 0.f; b1 = 0.f;
#pragma unroll
      for (int k = 0; k < 8; ++k) {
        u32x4 hh = hl4[k];
        float aa = (k & 1) ? a1 : a0;
        float bb = (k & 1) ? b1 : b0;
        aa = fdot2u(wA[k][0], hh[0], aa); aa = fdot2u(wA[k][1], hh[1], aa);
        aa = fdot2u(wA[k][2], hh[2], aa); aa = fdot2u(wA[k][3], hh[3], aa);
        bb = fdot2u(wB[k][0], hh[0], bb); bb = fdot2u(wB[k][1], hh[1], bb);
        bb = fdot2u(wB[k][2], hh[2], bb); bb = fdot2u(wB[k][3], hh[3], bb);
        if (k & 1) { a1 = aa; b1 = bb; } else { a0 = aa; b0 = bb; }
      }
      float pa = a0 + a1, pb = b0 + b1;
      uint32_t* pub = hx + (size_t)(tag & 3u) * SLOTW + pubrow;
      __hip_atomic_store(pub + e1, (tag << 16) | f16bits(pa),
                         __ATOMIC_RELAXED, __HIP_MEMORY_SCOPE_AGENT);
      __hip_atomic_store(pub + e2, (tag << 16) | f16bits(pb),
                         __ATOMIC_RELAXED, __HIP_MEMORY_SCOPE_AGENT);
    }

    // ---- wave0: prefetch streams(t+1), poll 16 peer partials, tail, stage h(t+1) ----
    if (wv == 0) {
      float cx_n = 0.f, dr_n = 0.f, xv_n = 0.f;
      if (t + 1 < TT) {
        size_t bn = (size_t)(t + 1) * 16384 + (size_t)batch * DD + e_g;
        cx_n = d_out[bn];
        dr_n = d_out[H0OFF + 16384 + bn];
        xv_n = x[bn];
      }
      const uint32_t* pp = pollbase + (size_t)(tag & 3u) * SLOTW;
      uint32_t v[16];
      bool ok;
      do {
        ok = true;
#pragma unroll
        for (int p = 0; p < 16; ++p)
          v[p] = __hip_atomic_load(pp + p * PSTRIDE, __ATOMIC_RELAXED,
                                   __HIP_MEMORY_SCOPE_AGENT);
#pragma unroll
        for (int p = 0; p < 16; ++p) ok &= ((v[p] >> 16) == tag);
      } while (!__all(ok));
      float s0 = (f16val(v[0]) + f16val(v[1])) + (f16val(v[2]) + f16val(v[3]));
      float s1 = (f16val(v[4]) + f16val(v[5])) + (f16val(v[6]) + f16val(v[7]));
      float s2 = (f16val(v[8]) + f16val(v[9])) + (f16val(v[10]) + f16val(v[11]));
      float s3 = (f16val(v[12]) + f16val(v[13])) + (f16val(v[14]) + f16val(v[15]));
      float hdot = (s0 + s1) + (s2 + s3);
      float dlt = sigmoid_fast(dr_c);
      float cand = tanh_fast(cx_c + hdot);
      float hn = fmaf(dlt, cand - h_own, h_own);
      size_t base = (size_t)t * 16384 + (size_t)batch * DD + e_g;
      float z = hn + xv_c + bgv;
      d_out[base] = hn * z * sigmoid_fast(z);   // out[t]  (overwrites consumed cand_x[t])
      d_out[H0OFF + 16384 + base] = hn;         // h[t+1]  (overwrites consumed delta_raw[t])
      float v0 = __shfl(hn, 2 * (lane & 31), 64);
      float v1 = __shfl(hn, 2 * (lane & 31) + 1, 64);
      if (t + 1 < TT && lane < 32)
        hls[(t + 1) & 1][lane] = f16bits(v0) | (f16bits(v1) << 16);
      h_own = hn; cx_c = cx_n; dr_c = dr_n; xv_c = xv_n;
    }
    __syncthreads();                            // h(t+1) staged; ONE barrier per step
  }
}

// ---------------- launch ----------------
extern "C" void kernel_launch(void* const* d_in, const int* in_sizes, int n_in,
                              void* d_out_v, int out_size, void* d_ws, size_t ws_size,
                              hipStream_t stream) {
  const float* x  = (const float*)d_in[0];
  const float* h0 = (const float*)d_in[1];
  const float* Wx = (const float*)d_in[2];
  const float* Wh = (const float*)d_in[3];
  const float* Wd = (const float*)d_in[4];
  const float* b  = (const float*)d_in[5];
  const float* bd = (const float*)d_in[6];
  const float* bg = (const float*)d_in[7];
  float* out = (float*)d_out_v;

  char* ws = (char*)d_ws;
  float* u    = (float*)(ws + 0);
  float* v    = (float*)(ws + 4096);
  float* t0   = (float*)(ws + 8192);
  float* sc   = (float*)(ws + 12288);
  uint32_t* hx = (uint32_t*)(ws + 16384);        // 4 slots * SLOTW words = ~4.06 MiB
  f16* WhH  = (f16*)(ws + 4280320);              // 2 MiB, ends ~6.08 MiB

  (void)hipMemsetAsync(hx, 0, (size_t)4 * SLOTW * 4, stream);  // clear ring tags

  k_u0<<<1, 512, 0, stream>>>(t0, u);
  for (int it = 0; it < 3; ++it) {
    k_mvT<<<4, 256, 0, stream>>>(Wh, u, t0);
    k_norm<<<1, 1024, 0, stream>>>(t0, v, 1e-8f);
    k_mv<<<16, 256, 0, stream>>>(Wh, v, t0);
    k_norm<<<1, 1024, 0, stream>>>(t0, u, 1e-8f);
  }
  k_sigma<<<1, 1024, 0, stream>>>(u, t0, sc);
  k_castWh<<<4096, 256, 0, stream>>>(Wh, sc, WhH);

  dim3 gg(256, 8, 1);
  k_gemm<<<gg, 256, 0, stream>>>(x, Wx, b, out);                   // cand_x -> out region
  k_gemm<<<gg, 256, 0, stream>>>(x, Wd, bd, out + H0OFF + 16384);  // delta_raw -> h region (+1)

  k_rec<<<256, 512, 0, stream>>>(x, h0, bg, WhH, hx, out);
}